// Round 12
// baseline (68.954 us; speedup 1.0000x reference)
//
#include <hip/hip_runtime.h>
#include <cstdint>
#include <cstddef>

typedef _Float16 f16x8 __attribute__((ext_vector_type(8)));
typedef _Float16 f16x4 __attribute__((ext_vector_type(4)));
typedef _Float16 f16x2 __attribute__((ext_vector_type(2)));
typedef float    f32x4 __attribute__((ext_vector_type(4)));

#define MFMA16(a,b,c) __builtin_amdgcn_mfma_f32_16x16x32_f16((a),(b),(c),0,0,0)

// ws layout (halfs) — weights in 16x16-MFMA fragment-linear order.
// Fragment convention (R1-verified): operand lane&15 = its D-index, k = 32kk+8*(l>>4)+j.
//   W1F  [15][4ot][8kk][64][8] @0       (245760)
//   W16F [4ot][12kk][64][8]    @245760  (24576)   sp=32kk+8(l>>4)+j; x col=1808+sp; zero sp<12 or sp>=368
//   W2F  [16t][8kk][64][8]     @270336  (65536)   t = z o-tile; g = t>>2
//   W3F  [17t][8kk][64][8]     @335872  (69632)   o>=260 zero
__global__ void tea_prep(const float* __restrict__ W1, const float* __restrict__ W16,
                         const float* __restrict__ W2, const float* __restrict__ W3,
                         _Float16* __restrict__ ws)
{
    int i = blockIdx.x * blockDim.x + threadIdx.x;
    if (i < 245760) {
        int win = i >> 14, t = i & 16383;
        int ot = t >> 12, kk = (t >> 9) & 7, l = (t >> 3) & 63, j = t & 7;
        int o = 16 * ot + (l & 15);
        int s = 32 * kk + 8 * (l >> 4) + j;
        ws[i] = (_Float16)W1[(win * 256 + s) * 64 + o];
    } else if (i < 270336) {
        int t = i - 245760;
        int ot = t / 6144, t2 = t % 6144;
        int kk = t2 >> 9, l = (t2 >> 3) & 63, j = t2 & 7;
        int o = 16 * ot + (l & 15);
        int sp = 32 * kk + 8 * (l >> 4) + j;
        ws[i] = (_Float16)((sp >= 12 && sp < 368) ? W16[(sp - 12) * 64 + o] : 0.f);
    } else if (i < 335872) {
        int t = i - 270336;
        int q = t >> 12, kk = (t >> 9) & 7, l = (t >> 3) & 63, j = t & 7;
        int og = 16 * q + (l & 15);
        int g = q >> 2, o2 = og - 64 * g;
        int s = 32 * kk + 8 * (l >> 4) + j;
        ws[i] = (_Float16)W2[(g * 256 + s) * 64 + o2];
    } else if (i < 405504) {
        int t = i - 335872;
        int tt = t >> 12, kk = (t >> 9) & 7, l = (t >> 3) & 63, j = t & 7;
        int o = 16 * tt + (l & 15);
        int s = 32 * kk + 8 * (l >> 4) + j;
        ws[i] = (_Float16)((o < 260) ? W3[s * 260 + o] : 0.f);
    }
}

// Fused, 16 rows/block, 1024 threads (16 waves), 2 blocks/CU.
// LDS sh[34952] halfs = 69904 B:
//   xsm  [16][2184] @0 (34944; +8 tail pad, pads zeroed)   dead after b1
//   ylds [16][1032] @0          (16512)  aliases xsm
//   zlds [16][264]  @16896      (4224)
//   ps   f32 [16][16][10] @h21504 (5120 halfs)
__global__ __launch_bounds__(1024, 8)
void tea_f16(const float* __restrict__ x,
             const float* __restrict__ b1,  const float* __restrict__ b16,
             const float* __restrict__ b2,  const float* __restrict__ b3,
             const _Float16* __restrict__ ws, float* __restrict__ out)
{
    __shared__ _Float16 sh[34952];
    const int tid = threadIdx.x;
    const int bid = blockIdx.x;
    const int wg  = (bid & 7) * 128 + (bid >> 3);     // bijective XCD swizzle (1024%8==0)
    const int q = tid >> 6, l = tid & 63, r = l & 15, kg = l >> 4;

    const float* xg = x + (size_t)wg * 16 * 2176;

#define BAR() do { \
    asm volatile("s_waitcnt lgkmcnt(0)" ::: "memory"); \
    __builtin_amdgcn_s_barrier(); \
    __builtin_amdgcn_sched_barrier(0); } while (0)

    // ---- zero pad halfs (NaN guard for y16 over-read) + stage x fp16 ----
    if (tid < 136) {
        if (tid < 128) sh[(tid >> 3) * 2184 + 2176 + (tid & 7)] = (_Float16)0.f;
        else           sh[34944 + tid - 128] = (_Float16)0.f;
    }
    {
        float4 S[8];
        float2 Sr;
        #pragma unroll
        for (int i = 0; i < 8; ++i) {
            int e = i * 4096 + tid * 4;
            S[i] = *(const float4*)(xg + (size_t)(e >> 11) * 2176 + (e & 2047));
        }
        Sr = *(const float2*)(xg + (size_t)(tid >> 6) * 2176 + 2048 + (tid & 63) * 2);
        #pragma unroll
        for (int i = 0; i < 8; ++i) {
            int e = i * 4096 + tid * 4;
            float4 u = S[i];
            f16x4 hv;
            hv[0] = (_Float16)u.x; hv[1] = (_Float16)u.y;
            hv[2] = (_Float16)u.z; hv[3] = (_Float16)u.w;
            *(f16x4*)&sh[(e >> 11) * 2184 + (e & 2047)] = hv;
        }
        {
            f16x2 hv;
            hv[0] = (_Float16)Sr.x; hv[1] = (_Float16)Sr.y;
            *(f16x2*)&sh[(tid >> 6) * 2184 + 2048 + (tid & 63) * 2] = hv;
        }
    }
    BAR();                                            // b0: x staged

    // ---- layer 1: wave q -> window q (q<15) or y16 (q==15); acc per o-tile ----
    f32x4 a0 = {0.f,0.f,0.f,0.f}, a1 = a0, a2 = a0, a3 = a0;
    if (q < 15) {
        const _Float16* A = ws + q * 16384;
        const int cb = 128 * q;
        #pragma unroll
        for (int kk = 0; kk < 8; ++kk) {
            f16x8 B  = *(const f16x8*)&sh[r * 2184 + cb + 32 * kk + 8 * kg];
            f16x8 A0 = *(const f16x8*)(A +          kk * 512 + l * 8);
            f16x8 A1 = *(const f16x8*)(A +  4096 +  kk * 512 + l * 8);
            f16x8 A2 = *(const f16x8*)(A +  8192 +  kk * 512 + l * 8);
            f16x8 A3 = *(const f16x8*)(A + 12288 +  kk * 512 + l * 8);
            a0 = MFMA16(A0, B, a0);
            a1 = MFMA16(A1, B, a1);
            a2 = MFMA16(A2, B, a2);
            a3 = MFMA16(A3, B, a3);
        }
    } else {
        const _Float16* A = ws + 245760;
        #pragma unroll
        for (int kk = 0; kk < 12; ++kk) {
            f16x8 B  = *(const f16x8*)&sh[r * 2184 + 1808 + 32 * kk + 8 * kg];
            f16x8 A0 = *(const f16x8*)(A +          kk * 512 + l * 8);
            f16x8 A1 = *(const f16x8*)(A +  6144 +  kk * 512 + l * 8);
            f16x8 A2 = *(const f16x8*)(A + 12288 +  kk * 512 + l * 8);
            f16x8 A3 = *(const f16x8*)(A + 18432 +  kk * 512 + l * 8);
            a0 = MFMA16(A0, B, a0);
            a1 = MFMA16(A1, B, a1);
            a2 = MFMA16(A2, B, a2);
            a3 = MFMA16(A3, B, a3);
        }
    }
    BAR();                                            // b1: all xsm reads retired

    // ---- y -> ylds (bias+relu+pack); wave q owns y cols [64q, 64q+64) ----
    {
        const float* bp = (q < 15) ? (b1 + q * 64) : b16;
        #pragma unroll
        for (int ot = 0; ot < 4; ++ot) {
            f32x4 a = (ot == 0) ? a0 : (ot == 1) ? a1 : (ot == 2) ? a2 : a3;
            float4 bv = *(const float4*)(bp + 16 * ot + 4 * kg);
            f16x4 pk;
            pk[0] = (_Float16)fmaxf(a[0] + bv.x, 0.f);
            pk[1] = (_Float16)fmaxf(a[1] + bv.y, 0.f);
            pk[2] = (_Float16)fmaxf(a[2] + bv.z, 0.f);
            pk[3] = (_Float16)fmaxf(a[3] + bv.w, 0.f);
            *(f16x4*)&sh[r * 1032 + 64 * q + 16 * ot + 4 * kg] = pk;
        }
    }
    BAR();                                            // b2: y published

    // ---- layer 2: wave q -> z o-tile q (o = 16q+..); K = y[256*(q>>2) ..+256) ----
    {
        const _Float16* A = ws + 270336 + q * 4096;
        const int yb = 256 * (q >> 2);
        f32x4 a = {0.f,0.f,0.f,0.f};
        #pragma unroll
        for (int kk = 0; kk < 8; ++kk) {
            f16x8 B  = *(const f16x8*)&sh[r * 1032 + yb + 32 * kk + 8 * kg];
            f16x8 A0 = *(const f16x8*)(A + kk * 512 + l * 8);
            a = MFMA16(A0, B, a);
        }
        float4 bv = *(const float4*)(b2 + 16 * q + 4 * kg);
        f16x4 pk;
        pk[0] = (_Float16)fmaxf(a[0] + bv.x, 0.f);
        pk[1] = (_Float16)fmaxf(a[1] + bv.y, 0.f);
        pk[2] = (_Float16)fmaxf(a[2] + bv.z, 0.f);
        pk[3] = (_Float16)fmaxf(a[3] + bv.w, 0.f);
        *(f16x4*)&sh[16896 + r * 264 + 16 * q + 4 * kg] = pk;
    }
    BAR();                                            // b3: z published

    // ---- layer 3: wave q -> o-tile q (wave 15 also tile 16); pool per lane ----
    float p[10];
    #pragma unroll
    for (int c = 0; c < 10; ++c) p[c] = 0.f;

    {
        const _Float16* A3 = ws + 335872 + q * 4096;
        f32x4 a = {0.f,0.f,0.f,0.f};
        #pragma unroll
        for (int kk = 0; kk < 8; ++kk) {
            f16x8 B  = *(const f16x8*)&sh[16896 + r * 264 + 32 * kk + 8 * kg];
            f16x8 A0 = *(const f16x8*)(A3 + kk * 512 + l * 8);
            a = MFMA16(A0, B, a);
        }
        #pragma unroll
        for (int t = 0; t < 4; ++t) {
            int o = 16 * q + 4 * kg + t;              // q<16 -> o<256 always valid
            float v = fmaxf(a[t] + b3[o], 0.f);
            p[(unsigned)o / 26u] += v;
        }
    }
    if (q == 15) {                                    // tail tile 16: o = 256..259 (kg==0)
        const _Float16* A3 = ws + 335872 + 16 * 4096;
        f32x4 a = {0.f,0.f,0.f,0.f};
        #pragma unroll
        for (int kk = 0; kk < 8; ++kk) {
            f16x8 B  = *(const f16x8*)&sh[16896 + r * 264 + 32 * kk + 8 * kg];
            f16x8 A0 = *(const f16x8*)(A3 + kk * 512 + l * 8);
            a = MFMA16(A0, B, a);
        }
        #pragma unroll
        for (int t = 0; t < 4; ++t) {
            int o = 256 + 4 * kg + t;
            if (o < 260) {
                float v = fmaxf(a[t] + b3[o], 0.f);
                p[(unsigned)o / 26u] += v;
            }
        }
    }
    // reduce the 4 k-groups (lanes r, r+16, r+32, r+48) -> full tile sum per row
    #pragma unroll
    for (int c = 0; c < 10; ++c) {
        p[c] += __shfl_xor(p[c], 16);
        p[c] += __shfl_xor(p[c], 32);
    }
    if (kg == 0) {
        float* ps = (float*)(sh + 21504);
        #pragma unroll
        for (int c = 0; c < 10; ++c) ps[q * 160 + r * 10 + c] = p[c];
    }
    BAR();                                            // b4: partials in

    // ---- reduce 16 wave-partials + softmax; threads 0..15 = rows ----
    if (tid < 16) {
        const float* ps = (const float*)(sh + 21504);
        float v[10];
        #pragma unroll
        for (int c = 0; c < 10; ++c) {
            float s = 0.f;
            #pragma unroll
            for (int j = 0; j < 16; ++j) s += ps[j * 160 + tid * 10 + c];
            v[c] = s;
        }
        float mx = v[0];
        #pragma unroll
        for (int c = 1; c < 10; ++c) mx = fmaxf(mx, v[c]);
        float e[10], se = 0.f;
        #pragma unroll
        for (int c = 0; c < 10; ++c) { e[c] = expf(v[c] - mx); se += e[c]; }
        float inv = 1.f / se;
        float* orow = out + (size_t)(wg * 16 + tid) * 10;
        #pragma unroll
        for (int c = 0; c < 10; ++c) orow[c] = e[c] * inv;
    }
#undef BAR
}

extern "C" void kernel_launch(void* const* d_in, const int* in_sizes, int n_in,
                              void* d_out, int out_size, void* d_ws, size_t ws_size,
                              hipStream_t stream)
{
    const float* x   = (const float*)d_in[0];
    const float* W1  = (const float*)d_in[1];
    const float* b1  = (const float*)d_in[2];
    const float* W16 = (const float*)d_in[3];
    const float* b16 = (const float*)d_in[4];
    const float* W2  = (const float*)d_in[5];
    const float* b2  = (const float*)d_in[6];
    const float* W3  = (const float*)d_in[7];
    const float* b3  = (const float*)d_in[8];
    float*    out = (float*)d_out;
    _Float16* ws  = (_Float16*)d_ws;

    tea_prep<<<1584, 256, 0, stream>>>(W1, W16, W2, W3, ws);
    tea_f16 <<<1024, 1024, 0, stream>>>(x, b1, b16, b2, b3, ws, out);
}